// Round 1
// 371.962 us; speedup vs baseline: 1.0492x; 1.0492x over previous
//
#include <hip/hip_runtime.h>
#include <cstddef>
#include <cstdint>

typedef unsigned short ushort_t;
typedef unsigned int uint_t;
typedef __attribute__((ext_vector_type(8))) short short8;
typedef __attribute__((ext_vector_type(4))) float f32x4;

#define EDIM 1024
#define NHEAD 16
#define HDIM 64
#define NB 4
#define LQ 512
#define SK 1024
#define BHD 64

__device__ __forceinline__ ushort_t f2b(float f) {
    uint_t u = __float_as_uint(f);
    return (ushort_t)((u + 0x7fffu + ((u >> 16) & 1u)) >> 16);
}
__device__ __forceinline__ float b2f(ushort_t b) {
    return __uint_as_float(((uint_t)b) << 16);
}

__device__ __forceinline__ void gload_lds16(const void* g, void* l) {
    __builtin_amdgcn_global_load_lds((const __attribute__((address_space(1))) void*)g,
                                     (__attribute__((address_space(3))) void*)l, 16, 0, 0);
}

// ============ mega projection GEMM: all 5 jobs in one balanced launch ======
// blocks 0..255:    K1 merged 3-product split precision -> K1f fp32 head-split
// blocks 256..511:  K2 merged 3-product                 -> K2f fp32 head-split
// blocks 512..767:  V1 (1-pass)                 -> V1b bf16 head-split
// blocks 768..1023: V2 (1-pass)                 -> V2b bf16 head-split
// blocks 1024..1407: QG (1-pass): q -> Qb bf16 head-split *0.125;
//                    g1/g2 -> G1b/G2b bf16 sigmoid flat
// All jobs use an XCD-aware tile remap (xcd = blockIdx%8 round-robin):
// each XCD owns a contiguous row-stripe (K/V) or col-stripe (QG) so the
// streamed operand is fetched from HBM on exactly one XCD's L2.
struct MegaArgs {
    const ushort_t *qx, *m1h, *m1l, *m2h, *m2l;
    const ushort_t *Wqg, *Wkv1, *Wkv2, *Wk1l, *Wk2l;
    const float *q_b, *k1_b, *k2_b, *v1_b, *v2_b, *g1_b, *g2_b;
    float *K1f, *K2f;
    ushort_t *V1b, *V2b, *Qb, *G1b, *G2b;
};

__global__ __launch_bounds__(256, 2)
void mega_gemm(MegaArgs a)
{
    __shared__ ushort_t As[128 * 64];
    __shared__ ushort_t Bs[128 * 64];
    const int tid = threadIdx.x;
    const int wave = tid >> 6, lane = tid & 63;
    const int ln = lane & 15, lq = lane >> 4;
    const int wm = wave & 1, wn = wave >> 1;
    const int mrl = lane >> 3;               // row within each 8-row staging group
    const int lswz = (lane & 7) ^ mrl;       // logical slot this lane stages

    const int id = blockIdx.x;
    f32x4 zero = {0.f, 0.f, 0.f, 0.f};

    if (id < 512) {
        // ===== merged split-precision K path: 3 products per 32-k step =====
        // LDS row layout (64 elems): logical slots 0..3 = hi k-chunk (8 elems
        // each), 4..7 = lo k-chunk; physical slot p at row r holds logical
        // p^(r&7) (same XOR swizzle as before, staged via per-lane global src).
        const int kind = id >> 8;
        const int t = id & 255;
        const int u = t >> 3;
        const int col0 = (u >> 2) * 128;                 // 8 col-panels
        const int row0 = ((t & 7) * 4 + (u & 3)) * 128;  // XCD owns 4-row stripe
        const ushort_t* Ah  = kind ? a.m2h : a.m1h;
        const ushort_t* Alo = kind ? a.m2l : a.m1l;
        const ushort_t* Bh  = kind ? a.Wkv2 : a.Wkv1;
        const ushort_t* Blo = kind ? a.Wk2l : a.Wk1l;
        const float* bias = kind ? a.k2_b : a.k1_b;

        f32x4 acc[4][4];
#pragma unroll
        for (int i = 0; i < 4; ++i)
#pragma unroll
            for (int j = 0; j < 4; ++j) acc[i][j] = zero;

        const int ksub = (lswz & 3) * 8;                 // k offset within 32-chunk
        const ushort_t* Asrc = (lswz & 4) ? Alo : Ah;    // per-lane hi/lo select
        const ushort_t* Bsrc = (lswz & 4) ? Blo : Bh;

        for (int kk = 0; kk < 1024; kk += 32) {
            __syncthreads();
#pragma unroll
            for (int j = 0; j < 4; ++j) {
                const int mr = (wave * 4 + j) * 8 + mrl;
                gload_lds16(Asrc + (size_t)(row0 + mr) * 1024 + kk + ksub,
                            (void*)(As + (wave * 4 + j) * 512));
                gload_lds16(Bsrc + (size_t)(col0 + mr) * 1024 + kk + ksub,
                            (void*)(Bs + (wave * 4 + j) * 512));
            }
            __syncthreads();
            short8 ah[4], alv[4], bh[4], blv[4];
#pragma unroll
            for (int i = 0; i < 4; ++i) {
                const int ml = wm * 64 + i * 16 + ln;
                const int pa = (lq ^ (ml & 7)) * 8;      // physical hi slot
                ah[i]  = *(const short8*)(As + ml * 64 + pa);
                alv[i] = *(const short8*)(As + ml * 64 + (pa ^ 32)); // lo = hi^4 slots
                const int nl = wn * 64 + i * 16 + ln;
                const int pb = (lq ^ (nl & 7)) * 8;
                bh[i]  = *(const short8*)(Bs + nl * 64 + pb);
                blv[i] = *(const short8*)(Bs + nl * 64 + (pb ^ 32));
            }
            // 48 MFMAs per barrier-pair; product-major order keeps the 16
            // acc chains independent between reuses.
#pragma unroll
            for (int i = 0; i < 4; ++i)
#pragma unroll
                for (int j = 0; j < 4; ++j)
                    acc[i][j] = __builtin_amdgcn_mfma_f32_16x16x32_bf16(ah[i], bh[j], acc[i][j], 0, 0, 0);
#pragma unroll
            for (int i = 0; i < 4; ++i)
#pragma unroll
                for (int j = 0; j < 4; ++j)
                    acc[i][j] = __builtin_amdgcn_mfma_f32_16x16x32_bf16(ah[i], blv[j], acc[i][j], 0, 0, 0);
#pragma unroll
            for (int i = 0; i < 4; ++i)
#pragma unroll
                for (int j = 0; j < 4; ++j)
                    acc[i][j] = __builtin_amdgcn_mfma_f32_16x16x32_bf16(alv[i], bh[j], acc[i][j], 0, 0, 0);
        }

        float* Y = kind ? a.K2f : a.K1f;
#pragma unroll
        for (int i = 0; i < 4; ++i) {
#pragma unroll
            for (int r = 0; r < 4; ++r) {
                const int row = row0 + wm * 64 + i * 16 + lq * 4 + r;
#pragma unroll
                for (int j = 0; j < 4; ++j) {
                    const int col = col0 + wn * 64 + j * 16 + ln;
                    const float v = acc[i][j][r] + bias[col];
                    const int s = row >> 2, b = row & 3, h = col >> 6, d = col & 63;
                    Y[(((size_t)(b * 16 + h)) * 1024 + s) * 64 + d] = v;
                }
            }
        }
        return;
    }

    // ===================== V / QG single-pass path =====================
    int kind, row0, col0;
    const ushort_t *A, *B;
    const float* bias;
    if (id < 1024) {
        int t = id - 512; kind = 2 + (t >> 8); t &= 255;
        const int u = t >> 3;
        col0 = (u >> 2) * 128;
        row0 = ((t & 7) * 4 + (u & 3)) * 128;           // XCD row-stripe
        A = (kind == 2) ? a.m1h : a.m2h;
        B = ((kind == 2) ? a.Wkv1 : a.Wkv2) + (size_t)1024 * 1024;
        bias = (kind == 2) ? a.v1_b : a.v2_b;
    } else {
        const int t = id - 1024; kind = 4;
        const int u = t >> 3;
        const int c = (t & 7) * 3 + (u >> 4);           // XCD owns 3 col-panels
        const int rr = u & 15;
        col0 = c * 128; row0 = rr * 128;
        A = a.qx; B = a.Wqg;
        const int seg = c >> 3;
        bias = (seg == 0) ? a.q_b : ((seg == 1) ? a.g1_b : a.g2_b);
    }

    f32x4 acc[4][4];
#pragma unroll
    for (int i = 0; i < 4; ++i)
#pragma unroll
        for (int j = 0; j < 4; ++j) acc[i][j] = zero;

    for (int kk = 0; kk < 1024; kk += 64) {
        __syncthreads();
#pragma unroll
        for (int j = 0; j < 4; ++j) {
            const int mr = (wave * 4 + j) * 8 + mrl;
            gload_lds16(A + (size_t)(row0 + mr) * 1024 + kk + lswz * 8,
                        (void*)(As + (wave * 4 + j) * 512));
            gload_lds16(B + (size_t)(col0 + mr) * 1024 + kk + lswz * 8,
                        (void*)(Bs + (wave * 4 + j) * 512));
        }
        __syncthreads();
#pragma unroll
        for (int sub = 0; sub < 2; ++sub) {
            short8 af[4], bfv[4];
#pragma unroll
            for (int i = 0; i < 4; ++i) {
                const int ml = wm * 64 + i * 16 + ln;
                af[i] = *(const short8*)(As + ml * 64 + (((sub * 4 + lq) ^ (ml & 7)) * 8));
                const int nl = wn * 64 + i * 16 + ln;
                bfv[i] = *(const short8*)(Bs + nl * 64 + (((sub * 4 + lq) ^ (nl & 7)) * 8));
            }
#pragma unroll
            for (int i = 0; i < 4; ++i)
#pragma unroll
                for (int j = 0; j < 4; ++j)
                    acc[i][j] = __builtin_amdgcn_mfma_f32_16x16x32_bf16(af[i], bfv[j], acc[i][j], 0, 0, 0);
        }
    }

#pragma unroll
    for (int i = 0; i < 4; ++i) {
#pragma unroll
        for (int r = 0; r < 4; ++r) {
            const int row = row0 + wm * 64 + i * 16 + lq * 4 + r;
#pragma unroll
            for (int j = 0; j < 4; ++j) {
                const int col = col0 + wn * 64 + j * 16 + ln;
                const int lc = col & 1023;
                float v = acc[i][j][r] + bias[lc];
                if (kind <= 3) {            // V bf16 head-split
                    const int s = row >> 2, b = row & 3, h = lc >> 6, d = lc & 63;
                    ushort_t* Y = (kind == 2) ? a.V1b : a.V2b;
                    Y[(((size_t)(b * 16 + h)) * 1024 + s) * 64 + d] = f2b(v);
                } else {
                    const int seg = col >> 10;
                    if (seg == 0) {         // Q bf16 head-split (L=512), *scale
                        v *= 0.125f;
                        const int s = row >> 2, b = row & 3, h = lc >> 6, d = lc & 63;
                        a.Qb[(((size_t)(b * 16 + h)) * 512 + s) * 64 + d] = f2b(v);
                    } else {                // gates bf16 sigmoid flat
                        v = 1.0f / (1.0f + __expf(-v));
                        ushort_t* Y = (seg == 1) ? a.G1b : a.G2b;
                        Y[(size_t)row * 1024 + lc] = f2b(v);
                    }
                }
            }
        }
    }
}

// =============== fused input/weight casts (one launch) ===============
struct CastArgs {
    const float* q; const float* m1; const float* m2;
    ushort_t* qx; ushort_t* m1h; ushort_t* m1l; ushort_t* m2h; ushort_t* m2l;
    const float* wsrc[8];
    ushort_t* whi[8];
    ushort_t* wlo[8];
};

__global__ __launch_bounds__(256)
void casts_kernel(CastArgs a)
{
    __shared__ float T[64][65];
    const int id = blockIdx.x;
    const int tid = threadIdx.x;
    if (id < 1024) {                       // query cast
        const size_t i = ((size_t)id * 256 + tid) * 8;
        float4 x = *(const float4*)(a.q + i);
        float4 y = *(const float4*)(a.q + i + 4);
        ushort_t o[8] = {f2b(x.x), f2b(x.y), f2b(x.z), f2b(x.w), f2b(y.x), f2b(y.y), f2b(y.z), f2b(y.w)};
        *(uint4*)( (void*)(a.qx + i) ) = *(const uint4*)o;
    } else if (id < 5120) {                // mod hi/lo split casts
        const int t = id - 1024;
        const int which = t >> 11;
        const float* x = which ? a.m2 : a.m1;
        ushort_t* yh = which ? a.m2h : a.m1h;
        ushort_t* yl = which ? a.m2l : a.m1l;
        const size_t i = ((size_t)(t & 2047) * 256 + tid) * 8;
        float v[8];
        *(float4*)v = *(const float4*)(x + i);
        *(float4*)(v + 4) = *(const float4*)(x + i + 4);
        ushort_t oh[8], ol[8];
#pragma unroll
        for (int k = 0; k < 8; ++k) {
            oh[k] = f2b(v[k]);
            ol[k] = f2b(v[k] - b2f(oh[k]));
        }
        *(uint4*)( (void*)(yh + i) ) = *(const uint4*)oh;
        *(uint4*)( (void*)(yl + i) ) = *(const uint4*)ol;
    } else {                               // weight transpose+cast
        const int t = id - 5120;
        const int z = t >> 8, x = t & 15, y = (t >> 4) & 15;
        const float* W = a.wsrc[z];
        ushort_t* Th = a.whi[z];
        ushort_t* Tl = a.wlo[z];
        const int k0 = x * 64, n0 = y * 64;
        const int r = tid >> 2, cg = (tid & 3) * 16;
#pragma unroll
        for (int u = 0; u < 4; ++u) {
            float4 v = *(const float4*)(W + (size_t)(k0 + r) * 1024 + n0 + cg + u * 4);
            T[r][cg + u * 4 + 0] = v.x; T[r][cg + u * 4 + 1] = v.y;
            T[r][cg + u * 4 + 2] = v.z; T[r][cg + u * 4 + 3] = v.w;
        }
        __syncthreads();
        ushort_t oh[16], ol[16];
#pragma unroll
        for (int u = 0; u < 16; ++u) {
            float v = T[cg + u][r];
            oh[u] = f2b(v);
            ol[u] = f2b(v - b2f(oh[u]));
        }
        ushort_t* dh = Th + (size_t)(n0 + r) * 1024 + k0 + cg;
        *(uint4*)( (void*)dh ) = *(const uint4*)oh;
        *(uint4*)( (void*)(dh + 8) ) = *(const uint4*)(oh + 8);
        if (Tl) {
            ushort_t* dl = Tl + (size_t)(n0 + r) * 1024 + k0 + cg;
            *(uint4*)( (void*)dl ) = *(const uint4*)ol;
            *(uint4*)( (void*)(dl + 8) ) = *(const uint4*)(ol + 8);
        }
    }
}

// ====== fused prep: K norms+cast, Q norms, V transpose (one launch) ======
__global__ __launch_bounds__(256)
void prep_kernel(const float* __restrict__ K1f, const float* __restrict__ K2f,
                 ushort_t* __restrict__ K1b, ushort_t* __restrict__ K2b,
                 float* __restrict__ vv, float* __restrict__ aa, float* __restrict__ va,
                 const ushort_t* __restrict__ Qb, float* __restrict__ ll,
                 const ushort_t* __restrict__ V1b, const ushort_t* __restrict__ V2b,
                 ushort_t* __restrict__ V1t, ushort_t* __restrict__ V2t)
{
    __shared__ float T[64][65];
    const int id = blockIdx.x;
    const int tid = threadIdx.x;
    const int wave = tid >> 6, lane = tid & 63;
    if (id < 16384) {                      // K norms (fp32) + bf16 cast
        const int row = id * 4 + wave;
        const float x1 = K1f[(size_t)row * 64 + lane];
        const float x2 = K2f[(size_t)row * 64 + lane];
        K1b[(size_t)row * 64 + lane] = f2b(x1);
        K2b[(size_t)row * 64 + lane] = f2b(x2);
        float s1 = x1 * x1, s2 = x2 * x2, s3 = x1 * x2;
#pragma unroll
        for (int o = 1; o < 64; o <<= 1) {
            s1 += __shfl_xor(s1, o);
            s2 += __shfl_xor(s2, o);
            s3 += __shfl_xor(s3, o);
        }
        if (lane == 0) { vv[row] = s1; aa[row] = s2; va[row] = s3; }
    } else if (id < 24576) {               // Q norms
        const int row = (id - 16384) * 4 + wave;
        const float x = b2f(Qb[(size_t)row * 64 + lane]);
        float s = x * x;
#pragma unroll
        for (int o = 1; o < 64; o <<= 1) s += __shfl_xor(s, o);
        if (lane == 0) ll[row] = s;
    } else {                               // V transpose
        const int t = id - 24576;
        const int z = t >> 10, bh = (t >> 4) & 63, s0 = (t & 15) * 64;
        const ushort_t* S = z ? V2b : V1b;
        ushort_t* D = z ? V2t : V1t;
        const int r = tid >> 2, cg = (tid & 3) * 16;
        ushort_t buf[16];
        const ushort_t* sp = S + ((size_t)bh * 1024 + s0 + r) * 64 + cg;
        *(uint4*)buf = *(const uint4*)sp;
        *(uint4*)(buf + 8) = *(const uint4*)(sp + 8);
#pragma unroll
        for (int u = 0; u < 16; ++u) T[r][cg + u] = b2f(buf[u]);
        __syncthreads();
        ushort_t o[16];
#pragma unroll
        for (int u = 0; u < 16; ++u) o[u] = f2b(T[cg + u][r]);
        ushort_t* d = D + ((size_t)bh * 64 + r) * 1024 + s0 + cg;
        *(uint4*)( (void*)d ) = *(const uint4*)o;
        *(uint4*)( (void*)(d + 8) ) = *(const uint4*)(o + 8);
    }
}

// =================== scores: logits = lv + la - 1.5*sqrt(det) =============
__global__ __launch_bounds__(256, 2)
void scores_kernel(const ushort_t* __restrict__ Qb, const ushort_t* __restrict__ K1b,
                   const ushort_t* __restrict__ K2b, const float* __restrict__ ll,
                   const float* __restrict__ vv, const float* __restrict__ aa,
                   const float* __restrict__ va, float* __restrict__ logits)
{
    __shared__ ushort_t Qs[128 * 64];
    __shared__ ushort_t K1s[128 * 64];
    __shared__ ushort_t K2s[128 * 64];
    __shared__ float llS[128], vvS[128], aaS[128], vaS[128];
    const int tid = threadIdx.x;
    const int wave = tid >> 6, lane = tid & 63;
    const int ln = lane & 15, lq = lane >> 4;
    const int wm = wave & 1, wn = wave >> 1;
    const int bh = blockIdx.z;
    const int l0 = blockIdx.y * 128, s0 = blockIdx.x * 128;
    const int cswz = (lane & 7) ^ ((lane >> 3) & 7);
    const int mrl = lane >> 3;

    if (tid < 128) {
        llS[tid] = ll[(size_t)bh * 512 + l0 + tid];
        vvS[tid] = vv[(size_t)bh * 1024 + s0 + tid];
        aaS[tid] = aa[(size_t)bh * 1024 + s0 + tid];
        vaS[tid] = va[(size_t)bh * 1024 + s0 + tid];
    }
#pragma unroll
    for (int j = 0; j < 4; ++j) {
        const int mr = (wave * 4 + j) * 8 + mrl;
        gload_lds16(Qb + ((size_t)bh * 512 + l0 + mr) * 64 + cswz * 8, (void*)(Qs + (wave * 4 + j) * 512));
        gload_lds16(K1b + ((size_t)bh * 1024 + s0 + mr) * 64 + cswz * 8, (void*)(K1s + (wave * 4 + j) * 512));
        gload_lds16(K2b + ((size_t)bh * 1024 + s0 + mr) * 64 + cswz * 8, (void*)(K2s + (wave * 4 + j) * 512));
    }
    __syncthreads();

    f32x4 zero = {0.f, 0.f, 0.f, 0.f};
    f32x4 lv[4][4], la[4][4];
#pragma unroll
    for (int i = 0; i < 4; ++i)
#pragma unroll
        for (int j = 0; j < 4; ++j) { lv[i][j] = zero; la[i][j] = zero; }

#pragma unroll
    for (int sub = 0; sub < 2; ++sub) {
        short8 qf[4], k1f[4], k2f[4];
#pragma unroll
        for (int i = 0; i < 4; ++i) {
            const int ml = wm * 64 + i * 16 + ln;
            qf[i] = *(const short8*)(Qs + ml * 64 + (((sub * 4 + lq) ^ (ml & 7)) * 8));
            const int nl = wn * 64 + i * 16 + ln;
            k1f[i] = *(const short8*)(K1s + nl * 64 + (((sub * 4 + lq) ^ (nl & 7)) * 8));
            k2f[i] = *(const short8*)(K2s + nl * 64 + (((sub * 4 + lq) ^ (nl & 7)) * 8));
        }
#pragma unroll
        for (int i = 0; i < 4; ++i)
#pragma unroll
            for (int j = 0; j < 4; ++j) {
                lv[i][j] = __builtin_amdgcn_mfma_f32_16x16x32_bf16(qf[i], k1f[j], lv[i][j], 0, 0, 0);
                la[i][j] = __builtin_amdgcn_mfma_f32_16x16x32_bf16(qf[i], k2f[j], la[i][j], 0, 0, 0);
            }
    }

#pragma unroll
    for (int i = 0; i < 4; ++i) {
#pragma unroll
        for (int r = 0; r < 4; ++r) {
            const int l_loc = wm * 64 + i * 16 + lq * 4 + r;
            const float LL = llS[l_loc];
#pragma unroll
            for (int j = 0; j < 4; ++j) {
                const int s_loc = wn * 64 + j * 16 + ln;
                const float VV = vvS[s_loc], AA = aaS[s_loc], VA = vaS[s_loc];
                const float LV = lv[i][j][r], LA = la[i][j][r];
                float det = LL * (VV * AA - VA * VA) - LV * (LV * AA - LA * VA) + LA * (LV * VA - LA * VV);
                det = fmaxf(det, 1e-8f);
                logits[((size_t)bh * 512 + l0 + l_loc) * 1024 + s0 + s_loc] = LV + LA - 1.5f * sqrtf(det);
            }
        }
    }
}

// ======= softmax (fp32 -> bf16 in place) fused with head-average ==========
__global__ __launch_bounds__(256)
void softmax_avg_kernel(float* __restrict__ logits, float* __restrict__ avg)
{
    __shared__ float part[4][1024];
    const int b = blockIdx.x >> 9, l = blockIdx.x & 511;
    const int wave = threadIdx.x >> 6, lane = threadIdx.x & 63;
    float pacc[16];
#pragma unroll
    for (int u = 0; u < 16; ++u) pacc[u] = 0.f;
#pragma unroll
    for (int jj = 0; jj < 4; ++jj) {
        const int h = wave * 4 + jj;
        float* rowp = logits + (((size_t)(b * 16 + h)) * 512 + l) * 1024;
        float4 v[4];
#pragma unroll
        for (int c = 0; c < 4; ++c) v[c] = *(const float4*)(rowp + c * 256 + lane * 4);
        float m = -3.4e38f;
#pragma unroll
        for (int c = 0; c < 4; ++c) m = fmaxf(m, fmaxf(fmaxf(v[c].x, v[c].y), fmaxf(v[c].z, v[c].w)));
#pragma unroll
        for (int o = 1; o < 64; o <<= 1) m = fmaxf(m, __shfl_xor(m, o));
        float s = 0.f;
#pragma unroll
        for (int c = 0; c < 4; ++c) {
            v[c].x = __expf(v[c].x - m); v[c].y = __expf(v[c].y - m);
            v[c].z = __expf(v[c].z - m); v[c].w = __expf(v[c].w - m);
            s += v[c].x + v[c].y + v[c].z + v[c].w;
        }
#pragma unroll
        for (int o = 1; o < 64; o <<= 1) s += __shfl_xor(s, o);
        const float inv = 1.0f / s;
        ushort_t* arow = (ushort_t*)rowp;
#pragma unroll
        for (int c = 0; c < 4; ++c) {
            const float p0 = v[c].x * inv, p1 = v[c].y * inv, p2 = v[c].z * inv, p3 = v[c].w * inv;
            ushort_t w[4] = {f2b(p0), f2b(p1), f2b(p2), f2b(p3)};
            *(uint2*)( (void*)(arow + c * 256 + lane * 4) ) = *(const uint2*)w;
            pacc[c * 4 + 0] += p0; pacc[c * 4 + 1] += p1;
            pacc[c * 4 + 2] += p2; pacc[c * 4 + 3] += p3;
        }
    }
#pragma unroll
    for (int c = 0; c < 4; ++c) {
        float4 pv = {pacc[c * 4 + 0], pacc[c * 4 + 1], pacc[c * 4 + 2], pacc[c * 4 + 3]};
        *(float4*)(&part[wave][c * 256 + lane * 4]) = pv;
    }
    __syncthreads();
    const int s0 = threadIdx.x * 4;
    float4 a0 = *(const float4*)(&part[0][s0]);
    float4 a1 = *(const float4*)(&part[1][s0]);
    float4 a2 = *(const float4*)(&part[2][s0]);
    float4 a3 = *(const float4*)(&part[3][s0]);
    float4 o;
    o.x = (a0.x + a1.x + a2.x + a3.x) * 0.0625f;
    o.y = (a0.y + a1.y + a2.y + a3.y) * 0.0625f;
    o.z = (a0.z + a1.z + a2.z + a3.z) * 0.0625f;
    o.w = (a0.w + a1.w + a2.w + a3.w) * 0.0625f;
    *(float4*)(avg + ((size_t)(b * 512 + l)) * 1024 + s0) = o;
}

// =================== PV (v1,v2) + gating -> tmp bf16 [t][E] ================
__global__ __launch_bounds__(256, 2)
void pv_gate_kernel(const ushort_t* __restrict__ attn, const ushort_t* __restrict__ V1t,
                    const ushort_t* __restrict__ V2t, const ushort_t* __restrict__ G1,
                    const ushort_t* __restrict__ G2, ushort_t* __restrict__ tmpb)
{
    __shared__ ushort_t Ps[128 * 64];
    __shared__ ushort_t V1s[64 * 64];
    __shared__ ushort_t V2s[64 * 64];
    const int tid = threadIdx.x;
    const int wave = tid >> 6, lane = tid & 63;
    const int ln = lane & 15, lq = lane >> 4;
    const int bh = blockIdx.y;
    const int l0 = blockIdx.x * 128;
    const int cswz = (lane & 7) ^ ((lane >> 3) & 7);
    const int mrl = lane >> 3;
    const int bq = bh >> 4, h = bh & 15;

    f32x4 zero = {0.f, 0.f, 0.f, 0.f};
    f32x4 acc1[2][4], acc2[2][4];
#pragma unroll
    for (int i = 0; i < 2; ++i)
#pragma unroll
        for (int j = 0; j < 4; ++j) { acc1[i][j] = zero; acc2[i][j] = zero; }

    for (int s0 = 0; s0 < 1024; s0 += 64) {
        __syncthreads();
#pragma unroll
        for (int j = 0; j < 4; ++j) {
            const int mr = (wave * 4 + j) * 8 + mrl;
            gload_lds16(attn + ((size_t)bh * 512 + l0 + mr) * 2048 + s0 + cswz * 8,
                        (void*)(Ps + (wave * 4 + j) * 512));
        }
#pragma unroll
        for (int j = 0; j < 2; ++j) {
            const int mv = (wave * 2 + j) * 8 + mrl;
            gload_lds16(V1t + ((size_t)bh * 64 + mv) * 1024 + s0 + cswz * 8,
                        (void*)(V1s + (wave * 2 + j) * 512));
            gload_lds16(V2t + ((size_t)bh * 64 + mv) * 1024 + s0 + cswz * 8,
                        (void*)(V2s + (wave * 2 + j) * 512));
        }
        __syncthreads();
#pragma unroll
        for (int sub = 0; sub < 2; ++sub) {
            short8 af[2], b1f[4], b2f_[4];
#pragma unroll
            for (int i = 0; i < 2; ++i) {
                const int ml = wave * 32 + i * 16 + ln;
                af[i] = *(const short8*)(Ps + ml * 64 + (((sub * 4 + lq) ^ (ml & 7)) * 8));
            }
#pragma unroll
            for (int j = 0; j < 4; ++j) {
                const int nl = j * 16 + ln;
                b1f[j] = *(const short8*)(V1s + nl * 64 + (((sub * 4 + lq) ^ (nl & 7)) * 8));
                b2f_[j] = *(const short8*)(V2s + nl * 64 + (((sub * 4 + lq) ^ (nl & 7)) * 8));
            }
#pragma unroll
            for (int i = 0; i < 2; ++i)
#pragma unroll
                for (int j = 0; j < 4; ++j) {
                    acc1[i][j] = __builtin_amdgcn_mfma_f32_16x16x32_bf16(af[i], b1f[j], acc1[i][j], 0, 0, 0);
                    acc2[i][j] = __builtin_amdgcn_mfma_f32_16x16x32_bf16(af[i], b2f_[j], acc2[i][j], 0, 0, 0);
                }
        }
    }

#pragma unroll
    for (int i = 0; i < 2; ++i) {
#pragma unroll
        for (int r = 0; r < 4; ++r) {
            const int l = l0 + wave * 32 + i * 16 + lq * 4 + r;
#pragma unroll
            for (int j = 0; j < 4; ++j) {
                const int d = j * 16 + ln;
                const size_t addr = ((size_t)l * 4 + bq) * 1024 + h * 64 + d;
                const float v = 0.5f * (acc1[i][j][r] * b2f(G1[addr]) + acc2[i][j][r] * b2f(G2[addr]));
                tmpb[addr] = f2b(v);
            }
        }
    }
}

// ============ o-proj: 64x128 tiles, 256 blocks (fixed coverage) ============
// per wave: 32 rows (wm) x 64 cols (wn); A staged 64 rows, B staged 128 rows
__global__ __launch_bounds__(256, 2)
void gemm_o64(const ushort_t* __restrict__ A, const ushort_t* __restrict__ B,
              const float* __restrict__ bias, float* __restrict__ Y)
{
    __shared__ ushort_t As[64 * 64];
    __shared__ ushort_t Bs[128 * 64];
    const int tid = threadIdx.x;
    const int wave = tid >> 6, lane = tid & 63;
    const int ln = lane & 15, lq = lane >> 4;
    const int row0 = blockIdx.y * 64, col0 = blockIdx.x * 128;
    const int wm = wave & 1, wn = wave >> 1;
    const int cswz = (lane & 7) ^ ((lane >> 3) & 7);
    const int mrl = lane >> 3;

    f32x4 zero = {0.f, 0.f, 0.f, 0.f};
    f32x4 acc[2][4];
#pragma unroll
    for (int i = 0; i < 2; ++i)
#pragma unroll
        for (int j = 0; j < 4; ++j) acc[i][j] = zero;

    for (int kk = 0; kk < 1024; kk += 64) {
        __syncthreads();
#pragma unroll
        for (int j = 0; j < 2; ++j) {       // A: 64 rows
            const int mr = (wave * 2 + j) * 8 + mrl;
            gload_lds16(A + (size_t)(row0 + mr) * 1024 + kk + cswz * 8,
                        (void*)(As + (wave * 2 + j) * 512));
        }
#pragma unroll
        for (int j = 0; j < 4; ++j) {       // B: 128 rows
            const int mr = (wave * 4 + j) * 8 + mrl;
            gload_lds16(B + (size_t)(col0 + mr) * 1024 + kk + cswz * 8,
                        (void*)(Bs + (wave * 4 + j) * 512));
        }
        __syncthreads();
#pragma unroll
        for (int sub = 0; sub < 2; ++sub) {
            short8 af[2], bfv[4];
#pragma unroll
            for (int i = 0; i < 2; ++i) {
                const int ml = wm * 32 + i * 16 + ln;
                af[i] = *(const short8*)(As + ml * 64 + (((sub * 4 + lq) ^ (ml & 7)) * 8));
            }
#pragma unroll
            for (int j = 0; j < 4; ++j) {
                const int nl = wn * 64 + j * 16 + ln;
                bfv[j] = *(const short8*)(Bs + nl * 64 + (((sub * 4 + lq) ^ (nl & 7)) * 8));
            }
#pragma unroll
            for (int i = 0; i < 2; ++i)
#pragma unroll
                for (int j = 0; j < 4; ++j)
                    acc[i][j] = __builtin_amdgcn_mfma_f32_16x16x32_bf16(af[i], bfv[j], acc[i][j], 0, 0, 0);
        }
    }

#pragma unroll
    for (int i = 0; i < 2; ++i) {
#pragma unroll
        for (int r = 0; r < 4; ++r) {
            const int row = row0 + wm * 32 + i * 16 + lq * 4 + r;
#pragma unroll
            for (int j = 0; j < 4; ++j) {
                const int col = col0 + wn * 64 + j * 16 + ln;
                Y[(size_t)row * 1024 + col] = acc[i][j][r] + bias[col];
            }
        }
    }
}

// ============================ launch ============================
extern "C" void kernel_launch(void* const* d_in, const int* in_sizes, int n_in,
                              void* d_out, int out_size, void* d_ws, size_t ws_size,
                              hipStream_t stream)
{
    const float* query = (const float*)d_in[0];
    const float* mod1  = (const float*)d_in[1];
    const float* mod2  = (const float*)d_in[2];
    const float* q_w  = (const float*)d_in[3];  const float* q_b  = (const float*)d_in[4];
    const float* k1_w = (const float*)d_in[5];  const float* k1_b = (const float*)d_in[6];
    const float* k2_w = (const float*)d_in[7];  const float* k2_b = (const float*)d_in[8];
    const float* v1_w = (const float*)d_in[9];  const float* v1_b = (const float*)d_in[10];
    const float* v2_w = (const float*)d_in[11]; const float* v2_b = (const float*)d_in[12];
    const float* g1_w = (const float*)d_in[13]; const float* g1_b = (const float*)d_in[14];
    const float* g2_w = (const float*)d_in[15]; const float* g2_b = (const float*)d_in[16];
    const float* o_w  = (const float*)d_in[17]; const float* o_b  = (const float*)d_in[18];
    float* out = (float*)d_out;

    const size_t MB = 1u << 20;
    char* w = (char*)d_ws;
    // persistent region (0..78 MB)
    ushort_t* Wqg  = (ushort_t*)(w + 0 * MB);    // 6 MB [q|g1|g2]^T
    ushort_t* Wkv1 = (ushort_t*)(w + 6 * MB);    // 4 MB [k1|v1]^T
    ushort_t* Wkv2 = (ushort_t*)(w + 10 * MB);   // 4 MB [k2|v2]^T
    ushort_t* Wo   = (ushort_t*)(w + 14 * MB);   // 2 MB
    ushort_t* Wk1l = (ushort_t*)(w + 16 * MB);   // 2 MB
    ushort_t* Wk2l = (ushort_t*)(w + 18 * MB);   // 2 MB
    ushort_t* qx   = (ushort_t*)(w + 20 * MB);   // 4 MB; dead after mega-GEMM
    ushort_t* tmpb = qx;                         // reuse for gated PV output
    ushort_t* Qb   = (ushort_t*)(w + 24 * MB);   // 4 MB (full 64*512*64)
    ushort_t* K1b  = (ushort_t*)(w + 28 * MB);   // 8 MB
    ushort_t* K2b  = (ushort_t*)(w + 36 * MB);   // 8 MB
    ushort_t* V1t  = (ushort_t*)(w + 44 * MB);   // 8 MB
    ushort_t* V2t  = (ushort_t*)(w + 52 * MB);   // 8 MB
    ushort_t* G1b  = (ushort_t*)(w + 60 * MB);   // 4 MB bf16 gates
    ushort_t* G2b  = (ushort_t*)(w + 64 * MB);   // 4 MB
    float* ll = (float*)(w + 68 * MB);                   // 128 KB
    float* vv = (float*)(w + 68 * MB + 256 * 1024);      // 256 KB
    float* aa = (float*)(w + 68 * MB + 512 * 1024);
    float* va = (float*)(w + 68 * MB + 768 * 1024);
    // logits region 78..206 MB; transient overlays all dead before scores:
    float* logits = (float*)(w + 78 * MB);       // 128 MB
    ushort_t* m1h = (ushort_t*)(w + 78 * MB);    // 8 MB  (dead after mega-GEMM)
    ushort_t* m2h = (ushort_t*)(w + 86 * MB);    // 8 MB
    ushort_t* m1l = (ushort_t*)(w + 94 * MB);    // 8 MB
    ushort_t* m2l = (ushort_t*)(w + 102 * MB);   // 8 MB
    float* K1f = (float*)(w + 110 * MB);         // 16 MB (dead after prep)
    float* K2f = (float*)(w + 126 * MB);         // 16 MB
    ushort_t* V1b = (ushort_t*)(w + 142 * MB);   // 8 MB (dead after prep)
    ushort_t* V2b = (ushort_t*)(w + 150 * MB);   // 8 MB
    ushort_t* attn = (ushort_t*)logits;          // bf16, row stride 2048 elems

    // 1) fused casts
    CastArgs ca;
    ca.q = query; ca.m1 = mod1; ca.m2 = mod2;
    ca.qx = qx; ca.m1h = m1h; ca.m1l = m1l; ca.m2h = m2h; ca.m2l = m2l;
    const float* srcs[8] = {q_w, g1_w, g2_w, k1_w, v1_w, k2_w, v2_w, o_w};
    ushort_t* his[8] = {Wqg, Wqg + (size_t)1024 * 1024, Wqg + (size_t)2048 * 1024,
                        Wkv1, Wkv1 + (size_t)1024 * 1024, Wkv2, Wkv2 + (size_t)1024 * 1024, Wo};
    ushort_t* los[8] = {nullptr, nullptr, nullptr, Wk1l, nullptr, Wk2l, nullptr, nullptr};
    for (int i = 0; i < 8; ++i) { ca.wsrc[i] = srcs[i]; ca.whi[i] = his[i]; ca.wlo[i] = los[i]; }
    casts_kernel<<<7168, 256, 0, stream>>>(ca);

    // 2) all projections, one balanced launch
    MegaArgs ma;
    ma.qx = qx; ma.m1h = m1h; ma.m1l = m1l; ma.m2h = m2h; ma.m2l = m2l;
    ma.Wqg = Wqg; ma.Wkv1 = Wkv1; ma.Wkv2 = Wkv2; ma.Wk1l = Wk1l; ma.Wk2l = Wk2l;
    ma.q_b = q_b; ma.k1_b = k1_b; ma.k2_b = k2_b; ma.v1_b = v1_b; ma.v2_b = v2_b;
    ma.g1_b = g1_b; ma.g2_b = g2_b;
    ma.K1f = K1f; ma.K2f = K2f; ma.V1b = V1b; ma.V2b = V2b;
    ma.Qb = Qb; ma.G1b = G1b; ma.G2b = G2b;
    mega_gemm<<<1408, 256, 0, stream>>>(ma);

    // 3) fused prep (K norms+cast, Q norms, V transpose)
    prep_kernel<<<26624, 256, 0, stream>>>(K1f, K2f, K1b, K2b, vv, aa, va,
                                           Qb, ll, V1b, V2b, V1t, V2t);

    // 4-7) attention + output projection
    scores_kernel<<<dim3(8, 4, 64), 256, 0, stream>>>(Qb, K1b, K2b, ll, vv, aa, va, logits);
    softmax_avg_kernel<<<2048, 256, 0, stream>>>(logits, out + (size_t)LQ * NB * EDIM);
    pv_gate_kernel<<<dim3(4, 64), 256, 0, stream>>>(attn, V1t, V2t, G1b, G2b, tmpb);
    gemm_o64<<<dim3(8, 32), 256, 0, stream>>>(tmpb, Wo, o_b, out);
}